// Round 2
// baseline (189.705 us; speedup 1.0000x reference)
//
#include <hip/hip_runtime.h>
#include <hip/hip_bf16.h>
#include <stdint.h>
#include <stddef.h>

// DecorrLoss: grad = 0.5*mean_C(offdiag) + 0.5*diag(mean(x^2)-1), corr_loss, whit_loss
// x: f32 [8,4096,1024] -> [M=32768][D=1024]
// Plan:
//   pass1: f32 read -> bf16 TRANSPOSED copy XbT [D][M] in ws; per-row sum(x^2), sum(x^4)
//   gemm : C = XbT * XbT^T via mfma_f32_16x16x32_bf16, 128^2 tiles, BK=32, split-K=8
//   epi  : reduce 8 partials, scale, diag fixup -> d_out[0..1048575]
//   fin  : scalars from row stats -> d_out[1048576], d_out[1048577]

#define D_DIM 1024
#define M_ROWS 32768
#define SPLITS 8
#define KCHUNK (M_ROWS / SPLITS)   // 4096
#define BK 32

typedef __attribute__((ext_vector_type(8))) short bf16x8;
typedef __attribute__((ext_vector_type(4))) float f32x4;

__device__ inline unsigned short f2bf(float f) {
  unsigned int b = __float_as_uint(f);
  return (unsigned short)((b + 0x7fffu + ((b >> 16) & 1u)) >> 16);  // RNE
}

__device__ inline void gload_lds16(const void* g, void* l) {
  __builtin_amdgcn_global_load_lds(
      (const __attribute__((address_space(1))) void*)g,
      (__attribute__((address_space(3))) void*)l,
      16, 0, 0);
}

// ---------------- pass 1: transpose+convert + row stats ----------------
// grid: 512 m-tiles x 16 c-tiles = 8192 blocks, 256 threads
__global__ __launch_bounds__(256) void k_pass1(const float* __restrict__ x,
                                               unsigned short* __restrict__ xt,
                                               float* __restrict__ rowss,
                                               float* __restrict__ rows4) {
  __shared__ unsigned short sh[64 * 76];  // 64 rows(m) x 64 cols(c), stride 76 shorts
  const int bid = blockIdx.x;
  const int m0 = (bid & 511) * 64;
  const int c0 = (bid >> 9) * 64;
  const int t = (int)threadIdx.x;
  const int r16 = t >> 4, cg = t & 15;

#pragma unroll
  for (int mi = 0; mi < 4; ++mi) {
    const int m = mi * 16 + r16;
    const float4 v = *(const float4*)(x + (size_t)(m0 + m) * D_DIM + c0 + cg * 4);
    const float q0 = v.x * v.x, q1 = v.y * v.y, q2 = v.z * v.z, q3 = v.w * v.w;
    float ss = q0 + q1 + q2 + q3;
    float s4 = q0 * q0 + q1 * q1 + q2 * q2 + q3 * q3;
#pragma unroll
    for (int off = 8; off; off >>= 1) {
      ss += __shfl_xor(ss, off, 16);
      s4 += __shfl_xor(s4, off, 16);
    }
    if (cg == 0) {
      atomicAdd(&rowss[m0 + m], ss);
      atomicAdd(&rows4[m0 + m], s4);
    }
    ushort4 pk;
    pk.x = f2bf(v.x); pk.y = f2bf(v.y); pk.z = f2bf(v.z); pk.w = f2bf(v.w);
    *(ushort4*)&sh[m * 76 + cg * 4] = pk;   // 8B aligned (m*152 + cg*8)
  }
  __syncthreads();

#pragma unroll
  for (int ci = 0; ci < 2; ++ci) {
    const int c = ci * 32 + (t >> 3);
    const int ms = (t & 7) * 8;
    unsigned int w0 = sh[(ms + 0) * 76 + c] | ((unsigned int)sh[(ms + 1) * 76 + c] << 16);
    unsigned int w1 = sh[(ms + 2) * 76 + c] | ((unsigned int)sh[(ms + 3) * 76 + c] << 16);
    unsigned int w2 = sh[(ms + 4) * 76 + c] | ((unsigned int)sh[(ms + 5) * 76 + c] << 16);
    unsigned int w3 = sh[(ms + 6) * 76 + c] | ((unsigned int)sh[(ms + 7) * 76 + c] << 16);
    uint4 pk; pk.x = w0; pk.y = w1; pk.z = w2; pk.w = w3;
    *(uint4*)(xt + (size_t)(c0 + c) * M_ROWS + m0 + ms) = pk;  // 16B aligned
  }
}

// ---------------- gemm: C = XbT * XbT^T (both [1024][32768] bf16, K-contiguous) -----
// grid: 8 splits x 8 ti x 8 tj = 512 blocks, 256 threads (4 waves, 64x64 each)
__global__ __launch_bounds__(256) void k_gemm(const unsigned short* __restrict__ xt,
                                              float* __restrict__ cpart) {
  __shared__ unsigned short As[128 * BK];
  __shared__ unsigned short Bs[128 * BK];
  const int bid = (int)blockIdx.x;
  const int s = bid >> 6;
  const int ti = (bid >> 3) & 7;
  const int tj = bid & 7;
  const int t = (int)threadIdx.x;
  const int l = t & 63, w = t >> 6;
  const int wr = w >> 1, wc = w & 1;
  const int r = l & 15, g = l >> 4;

  f32x4 acc[4][4];
#pragma unroll
  for (int m = 0; m < 4; ++m)
#pragma unroll
    for (int n = 0; n < 4; ++n) acc[m][n] = (f32x4){0.f, 0.f, 0.f, 0.f};

  const int gbase0 = t & ~63;
  const int gbase1 = 256 + (t & ~63);
  const int gA0 = gbase0 + l, gA1 = gbase1 + l;
  const size_t rowA0 = (size_t)(ti * 128 + (gA0 >> 2)) * M_ROWS + (gA0 & 3) * 8;
  const size_t rowA1 = (size_t)(ti * 128 + (gA1 >> 2)) * M_ROWS + (gA1 & 3) * 8;
  const size_t rowB0 = (size_t)(tj * 128 + (gA0 >> 2)) * M_ROWS + (gA0 & 3) * 8;
  const size_t rowB1 = (size_t)(tj * 128 + (gA1 >> 2)) * M_ROWS + (gA1 & 3) * 8;

  const int kbeg = s * KCHUNK;
  for (int k0 = kbeg; k0 < kbeg + KCHUNK; k0 += BK) {
    gload_lds16(xt + rowA0 + k0, &As[gbase0 * 8]);
    gload_lds16(xt + rowA1 + k0, &As[gbase1 * 8]);
    gload_lds16(xt + rowB0 + k0, &Bs[gbase0 * 8]);
    gload_lds16(xt + rowB1 + k0, &Bs[gbase1 * 8]);
    __syncthreads();

    bf16x8 av[4], bv[4];
#pragma unroll
    for (int m = 0; m < 4; ++m)
      av[m] = *(const bf16x8*)&As[(wr * 64 + m * 16 + r) * BK + g * 8];
#pragma unroll
    for (int n = 0; n < 4; ++n)
      bv[n] = *(const bf16x8*)&Bs[(wc * 64 + n * 16 + r) * BK + g * 8];

#pragma unroll
    for (int m = 0; m < 4; ++m)
#pragma unroll
      for (int n = 0; n < 4; ++n)
        acc[m][n] = __builtin_amdgcn_mfma_f32_16x16x32_bf16(av[m], bv[n], acc[m][n], 0, 0, 0);
    __syncthreads();
  }

  // C/D layout (m89-verified): col = lane&15, row = (lane>>4)*4 + reg
  float* cp = cpart + (size_t)s * D_DIM * D_DIM;
#pragma unroll
  for (int m = 0; m < 4; ++m) {
    const int rowb = ti * 128 + wr * 64 + m * 16 + g * 4;
#pragma unroll
    for (int n = 0; n < 4; ++n) {
      const int col = tj * 128 + wc * 64 + n * 16 + r;
#pragma unroll
      for (int q = 0; q < 4; ++q)
        cp[(size_t)(rowb + q) * D_DIM + col] = acc[m][n][q];
    }
  }
}

// ---------------- epilogue: reduce partials, scale, diag fixup ----------------
// grid 1024 x 256 threads; each thread one float4 of grad
__global__ __launch_bounds__(256) void k_epi(const float* __restrict__ cpart,
                                             float* __restrict__ out) {
  const int idx = (int)blockIdx.x * 256 + (int)threadIdx.x;  // 0..262143
  const int i = idx >> 8;
  const int j0 = (idx & 255) * 4;
  float c0 = 0.f, c1 = 0.f, c2 = 0.f, c3 = 0.f;
#pragma unroll
  for (int s = 0; s < SPLITS; ++s) {
    const float4 v = *(const float4*)(cpart + (size_t)s * D_DIM * D_DIM +
                                      (size_t)i * D_DIM + j0);
    c0 += v.x; c1 += v.y; c2 += v.z; c3 += v.w;
  }
  const float sc = 0.5f / (float)M_ROWS;
  float4 o;
  o.x = c0 * sc; o.y = c1 * sc; o.z = c2 * sc; o.w = c3 * sc;
  if (i >= j0 && i < j0 + 4) {
    const float cd = (i == j0) ? c0 : (i == j0 + 1) ? c1 : (i == j0 + 2) ? c2 : c3;
    const float dv = 0.5f * (cd / (float)M_ROWS - 1.0f);
    if (i == j0) o.x = dv; else if (i == j0 + 1) o.y = dv;
    else if (i == j0 + 2) o.z = dv; else o.w = dv;
  }
  *(float4*)(out + (size_t)i * D_DIM + j0) = o;
}

// ---------------- finalize scalars ----------------
__global__ __launch_bounds__(256) void k_fin(const float* __restrict__ rowss,
                                             const float* __restrict__ rows4,
                                             float* __restrict__ out) {
  __shared__ float sc[3][4];
  const int t = (int)threadIdx.x;
  float corr = 0.f, ss = 0.f, s4 = 0.f;
  for (int m = t; m < M_ROWS; m += 256) {
    const float a = rowss[m], b = rows4[m];
    corr += a * a - b;
    ss += a;
    s4 += b;
  }
#pragma unroll
  for (int off = 32; off; off >>= 1) {
    corr += __shfl_down(corr, off);
    ss += __shfl_down(ss, off);
    s4 += __shfl_down(s4, off);
  }
  const int wv = t >> 6, l = t & 63;
  if (l == 0) { sc[0][wv] = corr; sc[1][wv] = ss; sc[2][wv] = s4; }
  __syncthreads();
  if (t == 0) {
    double ct = 0.0, st = 0.0, qt = 0.0;
#pragma unroll
    for (int i = 0; i < 4; ++i) { ct += sc[0][i]; st += sc[1][i]; qt += sc[2][i]; }
    const double N = (double)M_ROWS * (double)D_DIM;     // 33554432
    out[1048576] = (float)(ct / (double)M_ROWS / ((double)D_DIM * (double)D_DIM));
    out[1048577] = (float)((qt - 2.0 * st + N) / N);
  }
}

extern "C" void kernel_launch(void* const* d_in, const int* in_sizes, int n_in,
                              void* d_out, int out_size, void* d_ws, size_t ws_size,
                              hipStream_t stream) {
  (void)in_sizes; (void)n_in; (void)out_size; (void)ws_size;
  const float* x = (const float*)d_in[0];
  float* out = (float*)d_out;
  char* ws = (char*)d_ws;

  // ws layout (requires ~100.9 MB):
  unsigned short* xt = (unsigned short*)ws;                       // 67,108,864 B
  float* rowss = (float*)(ws + 67108864);                         //    131,072 B
  float* rows4 = (float*)(ws + 67239936);                         //    131,072 B
  float* cpart = (float*)(ws + 67371008);                         // 33,554,432 B

  hipMemsetAsync(rowss, 0, 262144, stream);                       // rowss+rows4
  k_pass1<<<8192, 256, 0, stream>>>(x, xt, rowss, rows4);
  k_gemm<<<64 * SPLITS, 256, 0, stream>>>(xt, cpart);
  k_epi<<<1024, 256, 0, stream>>>(cpart, out);
  k_fin<<<1, 256, 0, stream>>>(rowss, rows4, out);
}

// Round 3
// 176.689 us; speedup vs baseline: 1.0737x; 1.0737x over previous
//
#include <hip/hip_runtime.h>
#include <hip/hip_bf16.h>
#include <stdint.h>
#include <stddef.h>

// DecorrLoss: grad = 0.5*mean_C(offdiag) + 0.5*diag(mean(x^2)-1), corr_loss, whit_loss
// x: f32 [8,4096,1024] -> [M=32768][D=1024]
//   pass1: f32 -> bf16 transposed XbT [D][M]; per-row sum(x^2), sum(x^4) partials (no atomics)
//   gemm : C = XbT*XbT^T, SYMMETRIC: only 36 upper-triangle 128x128 tiles, split-K S-way
//   epi1 : reduce S partials -> csum[36][128][128]
//   epi2 : emit full grad (mirror lower), scale, diag fixup
//   fin1/fin2: deterministic scalar losses

#define D_DIM 1024
#define M_ROWS 32768
#define BK 32
#define NKB (M_ROWS / BK)          // 1024 K-blocks
#define NTILES 36                  // 8*9/2 triangle tiles
#define TILE_ELEMS 16384           // 128*128

typedef __attribute__((ext_vector_type(8))) short bf16x8;
typedef __attribute__((ext_vector_type(4))) float f32x4;

__device__ inline unsigned short f2bf(float f) {
  unsigned int b = __float_as_uint(f);
  return (unsigned short)((b + 0x7fffu + ((b >> 16) & 1u)) >> 16);  // RNE
}

__device__ inline void gload_lds16(const void* g, void* l) {
  __builtin_amdgcn_global_load_lds(
      (const __attribute__((address_space(1))) void*)g,
      (__attribute__((address_space(3))) void*)l,
      16, 0, 0);
}

// ---------------- pass 1: transpose+convert + row-stat partials ----------------
// grid: 512 m-tiles x 16 c-tiles = 8192 blocks, 256 threads
__global__ __launch_bounds__(256) void k_pass1(const float* __restrict__ x,
                                               unsigned short* __restrict__ xt,
                                               float* __restrict__ rssp,
                                               float* __restrict__ rs4p) {
  __shared__ unsigned short sh[64 * 76];  // 64 m x 64 c, stride 76 shorts
  const int bid = blockIdx.x;
  const int m0 = (bid & 511) * 64;
  const int ct = bid >> 9;            // c-tile 0..15
  const int c0 = ct * 64;
  const int t = (int)threadIdx.x;
  const int r16 = t >> 4, cg = t & 15;

#pragma unroll
  for (int mi = 0; mi < 4; ++mi) {
    const int m = mi * 16 + r16;
    const float4 v = *(const float4*)(x + (size_t)(m0 + m) * D_DIM + c0 + cg * 4);
    const float q0 = v.x * v.x, q1 = v.y * v.y, q2 = v.z * v.z, q3 = v.w * v.w;
    float ss = q0 + q1 + q2 + q3;
    float s4 = q0 * q0 + q1 * q1 + q2 * q2 + q3 * q3;
#pragma unroll
    for (int off = 8; off; off >>= 1) {
      ss += __shfl_xor(ss, off, 16);
      s4 += __shfl_xor(s4, off, 16);
    }
    if (cg == 0) {
      rssp[ct * M_ROWS + m0 + m] = ss;   // each (ct,m) written exactly once
      rs4p[ct * M_ROWS + m0 + m] = s4;
    }
    ushort4 pk;
    pk.x = f2bf(v.x); pk.y = f2bf(v.y); pk.z = f2bf(v.z); pk.w = f2bf(v.w);
    *(ushort4*)&sh[m * 76 + cg * 4] = pk;
  }
  __syncthreads();

#pragma unroll
  for (int ci = 0; ci < 2; ++ci) {
    const int c = ci * 32 + (t >> 3);
    const int ms = (t & 7) * 8;
    unsigned int w0 = sh[(ms + 0) * 76 + c] | ((unsigned int)sh[(ms + 1) * 76 + c] << 16);
    unsigned int w1 = sh[(ms + 2) * 76 + c] | ((unsigned int)sh[(ms + 3) * 76 + c] << 16);
    unsigned int w2 = sh[(ms + 4) * 76 + c] | ((unsigned int)sh[(ms + 5) * 76 + c] << 16);
    unsigned int w3 = sh[(ms + 6) * 76 + c] | ((unsigned int)sh[(ms + 7) * 76 + c] << 16);
    uint4 pk; pk.x = w0; pk.y = w1; pk.z = w2; pk.w = w3;
    *(uint4*)(xt + (size_t)(c0 + c) * M_ROWS + m0 + ms) = pk;
  }
}

// ---------------- gemm: upper-triangle tiles only, split-K ----------------
// grid: S * 36 blocks, 256 threads (4 waves, 2x2 of 64x64)
__global__ __launch_bounds__(256) void k_gemm(const unsigned short* __restrict__ xt,
                                              float* __restrict__ cpart, int S) {
  __shared__ unsigned short As[128 * BK];
  __shared__ unsigned short Bs[128 * BK];
  const int bid = (int)blockIdx.x;
  const int s = bid / NTILES;
  const int tidx = bid - s * NTILES;
  int rem = tidx, ti = 0;
  while (rem >= 8 - ti) { rem -= 8 - ti; ++ti; }
  const int tj = ti + rem;
  const bool diag = (ti == tj);

  const int t = (int)threadIdx.x;
  const int l = t & 63, w = t >> 6;
  const int wr = w >> 1, wc = w & 1;
  const int r = l & 15, g = l >> 4;

  f32x4 acc[4][4];
#pragma unroll
  for (int m = 0; m < 4; ++m)
#pragma unroll
    for (int n = 0; n < 4; ++n) acc[m][n] = (f32x4){0.f, 0.f, 0.f, 0.f};

  const int gbase0 = t & ~63;
  const int gbase1 = 256 + (t & ~63);
  const int gA0 = gbase0 + l, gA1 = gbase1 + l;
  const size_t rowA0 = (size_t)(ti * 128 + (gA0 >> 2)) * M_ROWS + (gA0 & 3) * 8;
  const size_t rowA1 = (size_t)(ti * 128 + (gA1 >> 2)) * M_ROWS + (gA1 & 3) * 8;
  const size_t rowB0 = (size_t)(tj * 128 + (gA0 >> 2)) * M_ROWS + (gA0 & 3) * 8;
  const size_t rowB1 = (size_t)(tj * 128 + (gA1 >> 2)) * M_ROWS + (gA1 & 3) * 8;

  // K partition: NKB blocks of BK over S splits
  const int q = NKB / S, rr = NKB - q * S;
  const int kb0 = s * q + (s < rr ? s : rr);
  const int nkb = q + (s < rr ? 1 : 0);
  const int kbeg = kb0 * BK, kend = (kb0 + nkb) * BK;

  const unsigned short* Bsrc = diag ? As : Bs;

  for (int k0 = kbeg; k0 < kend; k0 += BK) {
    gload_lds16(xt + rowA0 + k0, &As[gbase0 * 8]);
    gload_lds16(xt + rowA1 + k0, &As[gbase1 * 8]);
    if (!diag) {
      gload_lds16(xt + rowB0 + k0, &Bs[gbase0 * 8]);
      gload_lds16(xt + rowB1 + k0, &Bs[gbase1 * 8]);
    }
    __syncthreads();

    bf16x8 av[4], bv[4];
#pragma unroll
    for (int m = 0; m < 4; ++m)
      av[m] = *(const bf16x8*)&As[(wr * 64 + m * 16 + r) * BK + g * 8];
#pragma unroll
    for (int n = 0; n < 4; ++n)
      bv[n] = *(const bf16x8*)&Bsrc[(wc * 64 + n * 16 + r) * BK + g * 8];

#pragma unroll
    for (int m = 0; m < 4; ++m)
#pragma unroll
      for (int n = 0; n < 4; ++n)
        acc[m][n] = __builtin_amdgcn_mfma_f32_16x16x32_bf16(av[m], bv[n], acc[m][n], 0, 0, 0);
    __syncthreads();
  }

  // C/D layout: col = lane&15, row = (lane>>4)*4 + reg. Tile-local 128x128 write.
  float* cp = cpart + ((size_t)s * NTILES + tidx) * TILE_ELEMS;
#pragma unroll
  for (int m = 0; m < 4; ++m) {
    const int rowb = wr * 64 + m * 16 + g * 4;
#pragma unroll
    for (int n = 0; n < 4; ++n) {
      const int col = wc * 64 + n * 16 + r;
#pragma unroll
      for (int qq = 0; qq < 4; ++qq)
        cp[(size_t)(rowb + qq) * 128 + col] = acc[m][n][qq];
    }
  }
}

// ---------------- epi1: reduce S partials -> csum ----------------
// grid 576 x 256, one float4 per thread over 36*16384 floats
__global__ __launch_bounds__(256) void k_epi1(const float* __restrict__ cpart,
                                              float* __restrict__ csum, int S) {
  const int g4 = ((int)blockIdx.x * 256 + (int)threadIdx.x) * 4;
  f32x4 a = (f32x4){0.f, 0.f, 0.f, 0.f};
  for (int s = 0; s < S; ++s) {
    const f32x4 v = *(const f32x4*)(cpart + (size_t)s * (NTILES * TILE_ELEMS) + g4);
    a += v;
  }
  *(f32x4*)(csum + g4) = a;
}

// ---------------- epi2: emit full grad, mirror lower, diag fixup ----------------
__global__ __launch_bounds__(256) void k_epi2(const float* __restrict__ csum,
                                              float* __restrict__ out) {
  const int idx = (int)blockIdx.x * 256 + (int)threadIdx.x;  // 0..262143
  const int i = idx >> 8;
  const int j0 = (idx & 255) * 4;
  const int ti = i >> 7, tj = j0 >> 7;
  const float sc = 0.5f / (float)M_ROWS;
  float4 o;
  if (ti <= tj) {
    const int src = ti * 8 - (ti * (ti - 1)) / 2 + tj - ti;
    const float4 v = *(const float4*)(csum + (size_t)src * TILE_ELEMS +
                                      (size_t)(i & 127) * 128 + (j0 & 127));
    o.x = v.x * sc; o.y = v.y * sc; o.z = v.z * sc; o.w = v.w * sc;
    if (i >= j0 && i < j0 + 4) {  // diagonal element in this float4
      const float cd = (i == j0) ? v.x : (i == j0 + 1) ? v.y : (i == j0 + 2) ? v.z : v.w;
      const float dv = 0.5f * (cd / (float)M_ROWS - 1.0f);
      if (i == j0) o.x = dv; else if (i == j0 + 1) o.y = dv;
      else if (i == j0 + 2) o.z = dv; else o.w = dv;
    }
  } else {
    const int src = tj * 8 - (tj * (tj - 1)) / 2 + ti - tj;
    const int jj = j0 & 127, ii = i & 127;
    const float* base = csum + (size_t)src * TILE_ELEMS + ii;
    o.x = base[(size_t)(jj + 0) * 128] * sc;
    o.y = base[(size_t)(jj + 1) * 128] * sc;
    o.z = base[(size_t)(jj + 2) * 128] * sc;
    o.w = base[(size_t)(jj + 3) * 128] * sc;
  }
  *(float4*)(out + (size_t)i * D_DIM + j0) = o;
}

// ---------------- fin1: row stats reduce over 16 c-tiles + block partials ----------------
__global__ __launch_bounds__(256) void k_fin1(const float* __restrict__ rssp,
                                              const float* __restrict__ rs4p,
                                              float* __restrict__ scp) {
  __shared__ float sm[3][4];
  const int t = (int)threadIdx.x;
  const int m = (int)blockIdx.x * 256 + t;
  float a = 0.f, b = 0.f;
#pragma unroll
  for (int ct = 0; ct < 16; ++ct) {
    a += rssp[ct * M_ROWS + m];
    b += rs4p[ct * M_ROWS + m];
  }
  float corr = a * a - b;
#pragma unroll
  for (int off = 32; off; off >>= 1) {
    corr += __shfl_down(corr, off);
    a += __shfl_down(a, off);
    b += __shfl_down(b, off);
  }
  const int wv = t >> 6;
  if ((t & 63) == 0) { sm[0][wv] = corr; sm[1][wv] = a; sm[2][wv] = b; }
  __syncthreads();
  if (t == 0) {
    float c4 = 0.f, a4 = 0.f, b4 = 0.f;
#pragma unroll
    for (int i = 0; i < 4; ++i) { c4 += sm[0][i]; a4 += sm[1][i]; b4 += sm[2][i]; }
    scp[(int)blockIdx.x * 4 + 0] = c4;
    scp[(int)blockIdx.x * 4 + 1] = a4;
    scp[(int)blockIdx.x * 4 + 2] = b4;
  }
}

// ---------------- fin2: final scalars ----------------
__global__ __launch_bounds__(128) void k_fin2(const float* __restrict__ scp,
                                              float* __restrict__ out) {
  __shared__ float sm[3][2];
  const int t = (int)threadIdx.x;  // 0..127
  float c = scp[t * 4 + 0], a = scp[t * 4 + 1], b = scp[t * 4 + 2];
#pragma unroll
  for (int off = 32; off; off >>= 1) {
    c += __shfl_down(c, off);
    a += __shfl_down(a, off);
    b += __shfl_down(b, off);
  }
  const int wv = t >> 6;
  if ((t & 63) == 0) { sm[0][wv] = c; sm[1][wv] = a; sm[2][wv] = b; }
  __syncthreads();
  if (t == 0) {
    const double ct = (double)sm[0][0] + (double)sm[0][1];
    const double st = (double)sm[1][0] + (double)sm[1][1];
    const double qt = (double)sm[2][0] + (double)sm[2][1];
    const double N = (double)M_ROWS * (double)D_DIM;
    out[1048576] = (float)(ct / (double)M_ROWS / ((double)D_DIM * (double)D_DIM));
    out[1048577] = (float)((qt - 2.0 * st + N) / N);
  }
}

extern "C" void kernel_launch(void* const* d_in, const int* in_sizes, int n_in,
                              void* d_out, int out_size, void* d_ws, size_t ws_size,
                              hipStream_t stream) {
  (void)in_sizes; (void)n_in; (void)out_size;
  const float* x = (const float*)d_in[0];
  float* out = (float*)d_out;
  char* ws = (char*)d_ws;

  // ws layout:
  unsigned short* xt = (unsigned short*)ws;                 // 67,108,864 B
  float* rssp = (float*)(ws + 67108864);                    //  2,097,152 B
  float* rs4p = (float*)(ws + 69206016);                    //  2,097,152 B
  float* scp  = (float*)(ws + 71303168);                    //      4,096 B
  float* csum = (float*)(ws + 71307264);                    //  2,359,296 B
  float* cpart = (float*)(ws + 73666560);                   //  S * 2,359,296 B
  const size_t base = 73666560;
  size_t avail = (ws_size > base) ? (ws_size - base) : 0;
  int S = (int)(avail / (sizeof(float) * NTILES * TILE_ELEMS));
  if (S > 32) S = 32;
  if (S < 1) S = 1;

  k_pass1<<<8192, 256, 0, stream>>>(x, xt, rssp, rs4p);
  k_gemm<<<NTILES * S, 256, 0, stream>>>(xt, cpart, S);
  k_epi1<<<576, 256, 0, stream>>>(cpart, csum, S);
  k_epi2<<<1024, 256, 0, stream>>>(csum, out);
  k_fin1<<<128, 256, 0, stream>>>(rssp, rs4p, scp);
  k_fin2<<<1, 128, 0, stream>>>(scp, out);
}

// Round 4
// 125.743 us; speedup vs baseline: 1.5087x; 1.4052x over previous
//
#include <hip/hip_runtime.h>
#include <hip/hip_bf16.h>
#include <stdint.h>
#include <stddef.h>

// DecorrLoss: grad = 0.5*mean_C(offdiag) + 0.5*diag(mean(x^2)-1), corr_loss, whit_loss
// x: f32 [8,4096,1024] -> [M=32768][D=1024]
//   pass1: f32 -> bf16 transposed XbT [D][M]; per-row sum(x^2), sum(x^4) partials
//   gemm : C = XbT*XbT^T, 36 upper-triangle 128x128 tiles, split-K, XCD-chunked:
//          bid = chunk*288 + tile*8 + xcd  ->  split s = chunk*8 + xcd.
//          All 36 tiles of one 2MB K-chunk co-resident on one XCD => L2-resident panels.
//   epi1 : reduce S partials -> csum[36][128][128]
//   epi2 : emit full grad (mirror lower), scale, diag fixup
//   fin1/fin2: deterministic scalar losses

#define D_DIM 1024
#define M_ROWS 32768
#define BK 32
#define NKB (M_ROWS / BK)          // 1024 K-blocks
#define NTILES 36                  // 8*9/2 triangle tiles
#define TILE_ELEMS 16384           // 128*128

typedef __attribute__((ext_vector_type(8))) short bf16x8;
typedef __attribute__((ext_vector_type(4))) float f32x4;

__device__ inline unsigned short f2bf(float f) {
  unsigned int b = __float_as_uint(f);
  return (unsigned short)((b + 0x7fffu + ((b >> 16) & 1u)) >> 16);  // RNE
}

__device__ inline void gload_lds16(const void* g, void* l) {
  __builtin_amdgcn_global_load_lds(
      (const __attribute__((address_space(1))) void*)g,
      (__attribute__((address_space(3))) void*)l,
      16, 0, 0);
}

// ---------------- pass 1: transpose+convert + row-stat partials ----------------
// grid: 512 m-tiles x 16 c-tiles = 8192 blocks, 256 threads
__global__ __launch_bounds__(256) void k_pass1(const float* __restrict__ x,
                                               unsigned short* __restrict__ xt,
                                               float* __restrict__ rssp,
                                               float* __restrict__ rs4p) {
  __shared__ unsigned short sh[64 * 76];  // 64 m x 64 c, stride 76 shorts
  const int bid = blockIdx.x;
  const int m0 = (bid & 511) * 64;
  const int ct = bid >> 9;            // c-tile 0..15
  const int c0 = ct * 64;
  const int t = (int)threadIdx.x;
  const int r16 = t >> 4, cg = t & 15;

#pragma unroll
  for (int mi = 0; mi < 4; ++mi) {
    const int m = mi * 16 + r16;
    const float4 v = *(const float4*)(x + (size_t)(m0 + m) * D_DIM + c0 + cg * 4);
    const float q0 = v.x * v.x, q1 = v.y * v.y, q2 = v.z * v.z, q3 = v.w * v.w;
    float ss = q0 + q1 + q2 + q3;
    float s4 = q0 * q0 + q1 * q1 + q2 * q2 + q3 * q3;
#pragma unroll
    for (int off = 8; off; off >>= 1) {
      ss += __shfl_xor(ss, off, 16);
      s4 += __shfl_xor(s4, off, 16);
    }
    if (cg == 0) {
      rssp[ct * M_ROWS + m0 + m] = ss;
      rs4p[ct * M_ROWS + m0 + m] = s4;
    }
    ushort4 pk;
    pk.x = f2bf(v.x); pk.y = f2bf(v.y); pk.z = f2bf(v.z); pk.w = f2bf(v.w);
    *(ushort4*)&sh[m * 76 + cg * 4] = pk;
  }
  __syncthreads();

#pragma unroll
  for (int ci = 0; ci < 2; ++ci) {
    const int c = ci * 32 + (t >> 3);
    const int ms = (t & 7) * 8;
    unsigned int w0 = sh[(ms + 0) * 76 + c] | ((unsigned int)sh[(ms + 1) * 76 + c] << 16);
    unsigned int w1 = sh[(ms + 2) * 76 + c] | ((unsigned int)sh[(ms + 3) * 76 + c] << 16);
    unsigned int w2 = sh[(ms + 4) * 76 + c] | ((unsigned int)sh[(ms + 5) * 76 + c] << 16);
    unsigned int w3 = sh[(ms + 6) * 76 + c] | ((unsigned int)sh[(ms + 7) * 76 + c] << 16);
    uint4 pk; pk.x = w0; pk.y = w1; pk.z = w2; pk.w = w3;
    *(uint4*)(xt + (size_t)(c0 + c) * M_ROWS + m0 + ms) = pk;
  }
}

// ---------------- gemm: upper-triangle tiles, split-K, XCD-chunked ----------------
// grid: S * 36 blocks, 256 threads (4 waves, 2x2 of 64x64). swz=1 => S%8==0 decode.
__global__ __launch_bounds__(256) void k_gemm(const unsigned short* __restrict__ xt,
                                              float* __restrict__ cpart, int S, int swz) {
  __shared__ unsigned short As[128 * BK];
  __shared__ unsigned short Bs[128 * BK];
  const int bid = (int)blockIdx.x;
  int s, tidx;
  if (swz) {
    const int xcd = bid & 7;
    tidx = (bid >> 3) % NTILES;
    const int chunk = bid / (8 * NTILES);
    s = chunk * 8 + xcd;
  } else {
    s = bid / NTILES;
    tidx = bid - s * NTILES;
  }
  int rem = tidx, ti = 0;
  while (rem >= 8 - ti) { rem -= 8 - ti; ++ti; }
  const int tj = ti + rem;
  const bool diag = (ti == tj);

  const int t = (int)threadIdx.x;
  const int l = t & 63, w = t >> 6;
  const int wr = w >> 1, wc = w & 1;
  const int r = l & 15, g = l >> 4;

  f32x4 acc[4][4];
#pragma unroll
  for (int m = 0; m < 4; ++m)
#pragma unroll
    for (int n = 0; n < 4; ++n) acc[m][n] = (f32x4){0.f, 0.f, 0.f, 0.f};

  const int gbase0 = t & ~63;
  const int gbase1 = 256 + (t & ~63);
  const int gA0 = gbase0 + l, gA1 = gbase1 + l;
  const size_t rowA0 = (size_t)(ti * 128 + (gA0 >> 2)) * M_ROWS + (gA0 & 3) * 8;
  const size_t rowA1 = (size_t)(ti * 128 + (gA1 >> 2)) * M_ROWS + (gA1 & 3) * 8;
  const size_t rowB0 = (size_t)(tj * 128 + (gA0 >> 2)) * M_ROWS + (gA0 & 3) * 8;
  const size_t rowB1 = (size_t)(tj * 128 + (gA1 >> 2)) * M_ROWS + (gA1 & 3) * 8;

  // K partition: NKB blocks of BK over S splits
  const int q = NKB / S, rr = NKB - q * S;
  const int kb0 = s * q + (s < rr ? s : rr);
  const int nkb = q + (s < rr ? 1 : 0);
  const int kbeg = kb0 * BK, kend = (kb0 + nkb) * BK;

  const unsigned short* Bsrc = diag ? As : Bs;

  for (int k0 = kbeg; k0 < kend; k0 += BK) {
    gload_lds16(xt + rowA0 + k0, &As[gbase0 * 8]);
    gload_lds16(xt + rowA1 + k0, &As[gbase1 * 8]);
    if (!diag) {
      gload_lds16(xt + rowB0 + k0, &Bs[gbase0 * 8]);
      gload_lds16(xt + rowB1 + k0, &Bs[gbase1 * 8]);
    }
    __syncthreads();

    bf16x8 av[4], bv[4];
#pragma unroll
    for (int m = 0; m < 4; ++m)
      av[m] = *(const bf16x8*)&As[(wr * 64 + m * 16 + r) * BK + g * 8];
#pragma unroll
    for (int n = 0; n < 4; ++n)
      bv[n] = *(const bf16x8*)&Bsrc[(wc * 64 + n * 16 + r) * BK + g * 8];

#pragma unroll
    for (int m = 0; m < 4; ++m)
#pragma unroll
      for (int n = 0; n < 4; ++n)
        acc[m][n] = __builtin_amdgcn_mfma_f32_16x16x32_bf16(av[m], bv[n], acc[m][n], 0, 0, 0);
    __syncthreads();
  }

  // C/D layout: col = lane&15, row = (lane>>4)*4 + reg. Tile-local 128x128 write.
  float* cp = cpart + ((size_t)s * NTILES + tidx) * TILE_ELEMS;
#pragma unroll
  for (int m = 0; m < 4; ++m) {
    const int rowb = wr * 64 + m * 16 + g * 4;
#pragma unroll
    for (int n = 0; n < 4; ++n) {
      const int col = wc * 64 + n * 16 + r;
#pragma unroll
      for (int qq = 0; qq < 4; ++qq)
        cp[(size_t)(rowb + qq) * 128 + col] = acc[m][n][qq];
    }
  }
}

// ---------------- epi1: reduce S partials -> csum ----------------
__global__ __launch_bounds__(256) void k_epi1(const float* __restrict__ cpart,
                                              float* __restrict__ csum, int S) {
  const int g4 = ((int)blockIdx.x * 256 + (int)threadIdx.x) * 4;
  f32x4 a = (f32x4){0.f, 0.f, 0.f, 0.f};
  for (int s = 0; s < S; ++s) {
    const f32x4 v = *(const f32x4*)(cpart + (size_t)s * (NTILES * TILE_ELEMS) + g4);
    a += v;
  }
  *(f32x4*)(csum + g4) = a;
}

// ---------------- epi2: emit full grad, mirror lower, diag fixup ----------------
__global__ __launch_bounds__(256) void k_epi2(const float* __restrict__ csum,
                                              float* __restrict__ out) {
  const int idx = (int)blockIdx.x * 256 + (int)threadIdx.x;  // 0..262143
  const int i = idx >> 8;
  const int j0 = (idx & 255) * 4;
  const int ti = i >> 7, tj = j0 >> 7;
  const float sc = 0.5f / (float)M_ROWS;
  float4 o;
  if (ti <= tj) {
    const int src = ti * 8 - (ti * (ti - 1)) / 2 + tj - ti;
    const float4 v = *(const float4*)(csum + (size_t)src * TILE_ELEMS +
                                      (size_t)(i & 127) * 128 + (j0 & 127));
    o.x = v.x * sc; o.y = v.y * sc; o.z = v.z * sc; o.w = v.w * sc;
    if (i >= j0 && i < j0 + 4) {
      const float cd = (i == j0) ? v.x : (i == j0 + 1) ? v.y : (i == j0 + 2) ? v.z : v.w;
      const float dv = 0.5f * (cd / (float)M_ROWS - 1.0f);
      if (i == j0) o.x = dv; else if (i == j0 + 1) o.y = dv;
      else if (i == j0 + 2) o.z = dv; else o.w = dv;
    }
  } else {
    const int src = tj * 8 - (tj * (tj - 1)) / 2 + ti - tj;
    const int jj = j0 & 127, ii = i & 127;
    const float* base = csum + (size_t)src * TILE_ELEMS + ii;
    o.x = base[(size_t)(jj + 0) * 128] * sc;
    o.y = base[(size_t)(jj + 1) * 128] * sc;
    o.z = base[(size_t)(jj + 2) * 128] * sc;
    o.w = base[(size_t)(jj + 3) * 128] * sc;
  }
  *(float4*)(out + (size_t)i * D_DIM + j0) = o;
}

// ---------------- fin1: row stats reduce over 16 c-tiles + block partials ----------------
__global__ __launch_bounds__(256) void k_fin1(const float* __restrict__ rssp,
                                              const float* __restrict__ rs4p,
                                              float* __restrict__ scp) {
  __shared__ float sm[3][4];
  const int t = (int)threadIdx.x;
  const int m = (int)blockIdx.x * 256 + t;
  float a = 0.f, b = 0.f;
#pragma unroll
  for (int ct = 0; ct < 16; ++ct) {
    a += rssp[ct * M_ROWS + m];
    b += rs4p[ct * M_ROWS + m];
  }
  float corr = a * a - b;
#pragma unroll
  for (int off = 32; off; off >>= 1) {
    corr += __shfl_down(corr, off);
    a += __shfl_down(a, off);
    b += __shfl_down(b, off);
  }
  const int wv = t >> 6;
  if ((t & 63) == 0) { sm[0][wv] = corr; sm[1][wv] = a; sm[2][wv] = b; }
  __syncthreads();
  if (t == 0) {
    float c4 = 0.f, a4 = 0.f, b4 = 0.f;
#pragma unroll
    for (int i = 0; i < 4; ++i) { c4 += sm[0][i]; a4 += sm[1][i]; b4 += sm[2][i]; }
    scp[(int)blockIdx.x * 4 + 0] = c4;
    scp[(int)blockIdx.x * 4 + 1] = a4;
    scp[(int)blockIdx.x * 4 + 2] = b4;
  }
}

// ---------------- fin2: final scalars ----------------
__global__ __launch_bounds__(128) void k_fin2(const float* __restrict__ scp,
                                              float* __restrict__ out) {
  __shared__ float sm[3][2];
  const int t = (int)threadIdx.x;  // 0..127
  float c = scp[t * 4 + 0], a = scp[t * 4 + 1], b = scp[t * 4 + 2];
#pragma unroll
  for (int off = 32; off; off >>= 1) {
    c += __shfl_down(c, off);
    a += __shfl_down(a, off);
    b += __shfl_down(b, off);
  }
  const int wv = t >> 6;
  if ((t & 63) == 0) { sm[0][wv] = c; sm[1][wv] = a; sm[2][wv] = b; }
  __syncthreads();
  if (t == 0) {
    const double ct = (double)sm[0][0] + (double)sm[0][1];
    const double st = (double)sm[1][0] + (double)sm[1][1];
    const double qt = (double)sm[2][0] + (double)sm[2][1];
    const double N = (double)M_ROWS * (double)D_DIM;
    out[1048576] = (float)(ct / (double)M_ROWS / ((double)D_DIM * (double)D_DIM));
    out[1048577] = (float)((qt - 2.0 * st + N) / N);
  }
}

extern "C" void kernel_launch(void* const* d_in, const int* in_sizes, int n_in,
                              void* d_out, int out_size, void* d_ws, size_t ws_size,
                              hipStream_t stream) {
  (void)in_sizes; (void)n_in; (void)out_size;
  const float* x = (const float*)d_in[0];
  float* out = (float*)d_out;
  char* ws = (char*)d_ws;

  // ws layout:
  unsigned short* xt = (unsigned short*)ws;                 // 67,108,864 B
  float* rssp = (float*)(ws + 67108864);                    //  2,097,152 B
  float* rs4p = (float*)(ws + 69206016);                    //  2,097,152 B
  float* scp  = (float*)(ws + 71303168);                    //      4,096 B
  float* csum = (float*)(ws + 71307264);                    //  2,359,296 B
  float* cpart = (float*)(ws + 73666560);                   //  S * 2,359,296 B
  const size_t base = 73666560;
  size_t avail = (ws_size > base) ? (ws_size - base) : 0;
  int S = (int)(avail / (sizeof(float) * NTILES * TILE_ELEMS));
  if (S > 32) S = 32;
  int swz = 0;
  if (S >= 8) { S &= ~7; swz = 1; }   // multiple of 8 -> XCD-chunked decode
  if (S < 1) S = 1;

  k_pass1<<<8192, 256, 0, stream>>>(x, xt, rssp, rs4p);
  k_gemm<<<NTILES * S, 256, 0, stream>>>(xt, cpart, S, swz);
  k_epi1<<<576, 256, 0, stream>>>(cpart, csum, S);
  k_epi2<<<1024, 256, 0, stream>>>(csum, out);
  k_fin1<<<128, 256, 0, stream>>>(rssp, rs4p, scp);
  k_fin2<<<1, 128, 0, stream>>>(scp, out);
}